// Round 12
// baseline (143.863 us; speedup 1.0000x reference)
//
#include <hip/hip_runtime.h>

// Trilinear feature-grid interpolation, v8.
// grid layout: [R][R][R][3] = [z][y][x][c], R=256, fp32 (192 MB).
//
// v7 (141.4us): init + block-agg scatter (sparse CAP bins) + slab gather.
// v8: k_gather becomes a cross-bin double-buffered pipeline: each block
// owns 16 consecutive bins (x-major for halo reuse), LDS = 2 slabs
// (64.8 KB -> 2 blocks/CU); per iteration {barrier (drains stage k via the
// implicit vmcnt(0)) -> issue stage k+1 into the other buffer -> compute
// bin k}. Staging latency hides under compute. Blocks XCD-chunked so each
// XCD owns contiguous z-slabs (L2 halo reuse). Scatter grid 256->512.

#define NB     8192
#define CAP    512u
#define GBLK   512
#define BPB    16                 // bins per gather block; 512 blocks total
#define CHUNKF 100                // floats per x-chunk (25 float4; 99 used)
#define NCHUNK 81                 // 9 z-rows x 9 y-rows
#define NF4    2025               // 81*25 float4 per slab
#define LDSF   8100               // floats = 32400 B per slab

// ws layout: binned[8192*512] float4 = 64MB, then cur[8192]
#define CUR_OFF   67108864u
#define NEEDED    (67108864u + 32768u)

typedef float f4v __attribute__((ext_vector_type(4)));
typedef float f2v __attribute__((ext_vector_type(2)));
typedef f4v f4u __attribute__((aligned(8)));
typedef f2v f2u __attribute__((aligned(8)));

__device__ __forceinline__ void cell_of(float p, int& l, float& t) {
    float s = p * 255.0f;
    int v = (int)floorf(s);
    v = v < 0 ? 0 : (v > 254 ? 254 : v);
    l = v;
    t = s - (float)v;
}

// bin bits: [zb:5][yb:5][xb:3]  (32x8x8 cells per bin)
__device__ __forceinline__ int fine_bin3(float px, float py, float pz) {
    int xl, yl, zl; float tx, ty, tz;
    cell_of(px, xl, tx);
    cell_of(py, yl, ty);
    cell_of(pz, zl, tz);
    return ((zl >> 3) << 8) | ((yl >> 3) << 3) | (xl >> 5);
}

__device__ __forceinline__ void direct_lerp(const float* __restrict__ grid,
                                            float* __restrict__ out, int i,
                                            int xl, int yl, int zl,
                                            float tx, float ty, float tz) {
    int b00 = (zl * 65536 + yl * 256 + xl) * 3;
    int b01 = b00 + 768, b10 = b00 + 196608, b11 = b10 + 768;
    float s00[6], s01[6], s10[6], s11[6];
#pragma unroll
    for (int k = 0; k < 6; ++k) s00[k] = grid[b00 + k];
#pragma unroll
    for (int k = 0; k < 6; ++k) s01[k] = grid[b01 + k];
#pragma unroll
    for (int k = 0; k < 6; ++k) s10[k] = grid[b10 + k];
#pragma unroll
    for (int k = 0; k < 6; ++k) s11[k] = grid[b11 + k];
#pragma unroll
    for (int c = 0; c < 3; ++c) {
        float c00 = s00[c] * (1.0f - tx) + s00[c + 3] * tx;
        float c01 = s01[c] * (1.0f - tx) + s01[c + 3] * tx;
        float c10 = s10[c] * (1.0f - tx) + s10[c + 3] * tx;
        float c11 = s11[c] * (1.0f - tx) + s11[c + 3] * tx;
        float c0 = c00 * (1.0f - ty) + c01 * ty;
        float c1 = c10 * (1.0f - ty) + c11 * ty;
        out[3 * i + c] = c0 * (1.0f - tz) + c1 * tz;
    }
}

// ---------------- pass 0: init cursors to region bases ----------------
__global__ __launch_bounds__(1024) void k_init(unsigned* __restrict__ cur) {
    int i = blockIdx.x * 1024 + threadIdx.x;
    if (i < NB) cur[i] = (unsigned)i * CAP;
}

// ---------------- pass 1: block-aggregated scatter (2 pts/thread) ----------------
__global__ __launch_bounds__(1024) void k_scatter(const float* __restrict__ inp,
                                                  const float* __restrict__ grid,
                                                  float4* __restrict__ binned,
                                                  unsigned* __restrict__ cur,
                                                  float* __restrict__ out, int n) {
    __shared__ unsigned cnt[NB];
    __shared__ unsigned base[NB];
    int t = threadIdx.x;
    int P = n >> 1;
    int stride = gridDim.x * 1024;
    int iters = (P + stride - 1) / stride;

    if ((n & 1) && blockIdx.x == 0 && t == 0) {
        int i = n - 1;
        float px = inp[3 * i], py = inp[3 * i + 1], pz = inp[3 * i + 2];
        int b = fine_bin3(px, py, pz);
        unsigned r = atomicAdd(&cur[b], 1u);
        if (r - (unsigned)b * CAP < CAP) {
            float4 v; v.x = px; v.y = py; v.z = pz; v.w = __uint_as_float((unsigned)i);
            binned[r] = v;
        } else {
            int xl, yl, zl; float tx, ty, tz;
            cell_of(px, xl, tx); cell_of(py, yl, ty); cell_of(pz, zl, tz);
            direct_lerp(grid, out, i, xl, yl, zl, tx, ty, tz);
        }
    }

    for (int it = 0; it < iters; ++it) {
        int pr = it * stride + blockIdx.x * 1024 + t;
        for (int k = t; k < NB; k += 1024) cnt[k] = 0;
        __syncthreads();
        int b0 = 0, b1 = 0; unsigned r0 = 0, r1 = 0;
        float4 p0, p1;
        bool valid = (pr < P);
        if (valid) {
            f4v a = *(const f4u*)(inp + 6 * pr);
            f2v b = *(const f2u*)(inp + 6 * pr + 4);
            p0.x = a.x; p0.y = a.y; p0.z = a.z;
            p0.w = __uint_as_float((unsigned)(2 * pr));
            p1.x = a.w; p1.y = b.x; p1.z = b.y;
            p1.w = __uint_as_float((unsigned)(2 * pr + 1));
            b0 = fine_bin3(p0.x, p0.y, p0.z);
            b1 = fine_bin3(p1.x, p1.y, p1.z);
            r0 = atomicAdd(&cnt[b0], 1u);
            r1 = atomicAdd(&cnt[b1], 1u);
        }
        __syncthreads();
        for (int k = t; k < NB; k += 1024)
            if (cnt[k]) base[k] = atomicAdd(&cur[k], cnt[k]);
        __syncthreads();
        if (valid) {
            unsigned s0 = base[b0] + r0;
            unsigned s1 = base[b1] + r1;
            if (s0 - (unsigned)b0 * CAP < CAP) binned[s0] = p0;
            else {
                int xl, yl, zl; float tx, ty, tz;
                cell_of(p0.x, xl, tx); cell_of(p0.y, yl, ty); cell_of(p0.z, zl, tz);
                direct_lerp(grid, out, 2 * pr, xl, yl, zl, tx, ty, tz);
            }
            if (s1 - (unsigned)b1 * CAP < CAP) binned[s1] = p1;
            else {
                int xl, yl, zl; float tx, ty, tz;
                cell_of(p1.x, xl, tx); cell_of(p1.y, yl, ty); cell_of(p1.z, zl, tz);
                direct_lerp(grid, out, 2 * pr + 1, xl, yl, zl, tx, ty, tz);
            }
        }
        __syncthreads();
    }
}

// ---------------- pass 2: pipelined LDS-staged gather ----------------
// Issue the slab-stage DMA stream for `bin` into LDS buffer `dst`.
#define STAGE_SLAB(binv, dst)                                                   \
    do {                                                                        \
        int x0_ = ((binv) & 7) << 5;                                            \
        int y0_ = (((binv) >> 3) & 31) << 3;                                    \
        int z0_ = ((binv) >> 8) << 3;                                           \
        for (int u = t; u < NF4; u += GBLK) {                                   \
            int chunk = u / 25;                                                 \
            int j = u - chunk * 25;                                             \
            int zc = chunk / 9;                                                 \
            int yc = chunk - zc * 9;                                            \
            int zg = z0_ + zc; zg = zg > 255 ? 255 : zg;                        \
            int yg = y0_ + yc; yg = yg > 255 ? 255 : yg;                        \
            int joff = (j == 24 && x0_ == 224) ? 0 : (j << 2);                  \
            const float* src =                                                  \
                grid + (size_t)((zg << 16) | (yg << 8) | x0_) * 3 + joff;       \
            __builtin_amdgcn_global_load_lds(                                   \
                (const __attribute__((address_space(1))) unsigned int*)src,     \
                (__attribute__((address_space(3))) unsigned int*)&(dst)[(size_t)u * 4], \
                16, 0, 0);                                                      \
        }                                                                       \
    } while (0)

__global__ __launch_bounds__(GBLK) void k_gather(const float4* __restrict__ binned,
                                                 const float* __restrict__ grid,
                                                 const unsigned* __restrict__ cur,
                                                 float* __restrict__ out) {
    __shared__ __align__(16) float slab[2][LDSF];
    int t = threadIdx.x;
    // 512 blocks; XCD-chunked: XCD k owns blocks with blockIdx%8==k ->
    // bins [1024k, 1024k+1024) = 4 contiguous z-layers (L2 halo reuse).
    int sb = ((blockIdx.x & 7) << 6) | (blockIdx.x >> 3);   // bijective on [0,512)
    int bin0 = sb * BPB;

    STAGE_SLAB(bin0, slab[0]);

    for (int k = 0; k < BPB; ++k) {
        int bin = bin0 + k;
        int cb = k & 1;
        // __syncthreads emits s_waitcnt vmcnt(0) lgkmcnt(0) + s_barrier:
        // drains stage(k) so slab[cb] is ready, and separates last iter's
        // reads of slab[cb^1] from the staging below.
        __syncthreads();
        if (k + 1 < BPB) STAGE_SLAB(bin + 1, slab[cb ^ 1]);   // flies under compute

        int x0 = (bin & 7) << 5;
        int y0 = ((bin >> 3) & 31) << 3;
        int z0 = (bin >> 8) << 3;
        unsigned start = (unsigned)bin * CAP;
        unsigned count = cur[bin] - start;
        if (count > CAP) count = CAP;

        for (unsigned p = (unsigned)t; p < count; p += (unsigned)GBLK) {
            float4 v = binned[start + p];
            unsigned idx = __float_as_uint(v.w);

            int xl, yl, zl; float tx, ty, tz;
            cell_of(v.x, xl, tx);
            cell_of(v.y, yl, ty);
            cell_of(v.z, zl, tz);
            int xc = xl - x0, yc = yl - y0, zc = zl - z0;

            int r0 = (zc * 9 + yc) * CHUNKF + xc * 3;
            int e = r0 & ~1;
            bool d = (r0 & 1) != 0;

#define SEG_READ(b, s)                                       \
            do {                                             \
                f2v q0 = *(const f2u*)(&slab[cb][(b)]);      \
                f2v q1 = *(const f2u*)(&slab[cb][(b) + 2]);  \
                f2v q2 = *(const f2u*)(&slab[cb][(b) + 4]);  \
                f2v q3 = *(const f2u*)(&slab[cb][(b) + 6]);  \
                s[0] = d ? q0.y : q0.x;                      \
                s[1] = d ? q1.x : q0.y;                      \
                s[2] = d ? q1.y : q1.x;                      \
                s[3] = d ? q2.x : q1.y;                      \
                s[4] = d ? q2.y : q2.x;                      \
                s[5] = d ? q3.x : q2.y;                      \
            } while (0)

            float s00[6], s01[6], s10[6], s11[6];
            SEG_READ(e,               s00);   // (zc,   yc)
            SEG_READ(e + CHUNKF,      s01);   // (zc,   yc+1)
            SEG_READ(e + 9 * CHUNKF,  s10);   // (zc+1, yc)
            SEG_READ(e + 10 * CHUNKF, s11);   // (zc+1, yc+1)
#undef SEG_READ

            float o[3];
#pragma unroll
            for (int c = 0; c < 3; ++c) {
                float c00 = s00[c] * (1.0f - tx) + s00[c + 3] * tx;
                float c01 = s01[c] * (1.0f - tx) + s01[c + 3] * tx;
                float c10 = s10[c] * (1.0f - tx) + s10[c + 3] * tx;
                float c11 = s11[c] * (1.0f - tx) + s11[c + 3] * tx;
                float c0 = c00 * (1.0f - ty) + c01 * ty;
                float c1 = c10 * (1.0f - ty) + c11 * ty;
                o[c] = c0 * (1.0f - tz) + c1 * tz;
            }
            float3 w; w.x = o[0]; w.y = o[1]; w.z = o[2];
            *(float3*)(out + 3 * (size_t)idx) = w;
        }
    }
}

// ---------------- fallback: direct ----------------
__global__ __launch_bounds__(256) void k_direct(const float* __restrict__ inp,
                                                const float* __restrict__ grid,
                                                float* __restrict__ out, int n) {
    int i = blockIdx.x * blockDim.x + threadIdx.x;
    if (i >= n) return;
    int xl, yl, zl; float tx, ty, tz;
    cell_of(inp[3 * i + 0], xl, tx);
    cell_of(inp[3 * i + 1], yl, ty);
    cell_of(inp[3 * i + 2], zl, tz);
    direct_lerp(grid, out, i, xl, yl, zl, tx, ty, tz);
}

extern "C" void kernel_launch(void* const* d_in, const int* in_sizes, int n_in,
                              void* d_out, int out_size, void* d_ws, size_t ws_size,
                              hipStream_t stream) {
    const float* inp  = (const float*)d_in[0];  // [N][3]
    const float* grid = (const float*)d_in[1];  // [256][256][256][3]
    float* out = (float*)d_out;                 // [N][3]
    int n = in_sizes[0] / 3;

    if (ws_size < (size_t)NEEDED) {
        int blocks = (n + 255) / 256;
        k_direct<<<blocks, 256, 0, stream>>>(inp, grid, out, n);
        return;
    }

    char* ws = (char*)d_ws;
    float4*   binned = (float4*)ws;
    unsigned* cur    = (unsigned*)(ws + CUR_OFF);

    k_init   <<<8,        1024, 0, stream>>>(cur);
    k_scatter<<<512,      1024, 0, stream>>>(inp, grid, binned, cur, out, n);
    k_gather <<<NB / BPB, GBLK, 0, stream>>>(binned, grid, cur, out);
}

// Round 13
// 136.831 us; speedup vs baseline: 1.0514x; 1.0514x over previous
//
#include <hip/hip_runtime.h>

// Trilinear feature-grid interpolation, v9.
// grid layout: [R][R][R][3] = [z][y][x][c], R=256, fp32 (192 MB).
//
// Round-12 evidence: gather stuck at ~115us across slab shapes/pipelines;
// staging request-service caps at ~2.3 TB/s because slabs were 81 scattered
// 400B chunks + 8x x-split row re-reads. v9: block = (8 y-cells x FULL x
// x 16 z-cells); a z-layer's y-slab [z][y0..y0+8][*] is one CONTIGUOUS
// 27.6 KB read. Rolling 3-layer LDS window (82.9 KB), walk z staging layer
// z+2 while computing cell z. Staged 240 MB, all long sequential bursts.
// Scatter: 8192 fine bins keyed (zl, yl>>3), block-aggregated, CAP-strided.

#define NB     8192
#define CAP    512u
#define GBLK   1024
#define LAYERF4 1728              // float4 per staged layer (9 rows x 768 floats)
#define LAYERF  6912              // floats per layer
#define GRIDF4  12582912          // total float4 in grid

// ws layout: binned[8192*512] float4 = 64MB, then cur[8192]
#define CUR_OFF   67108864u
#define NEEDED    (67108864u + 32768u)

typedef float f4v __attribute__((ext_vector_type(4)));
typedef float f2v __attribute__((ext_vector_type(2)));
typedef f4v f4u __attribute__((aligned(8)));
typedef f2v f2u __attribute__((aligned(8)));

__device__ __forceinline__ void cell_of(float p, int& l, float& t) {
    float s = p * 255.0f;
    int v = (int)floorf(s);
    v = v < 0 ? 0 : (v > 254 ? 254 : v);
    l = v;
    t = s - (float)v;
}

// fine bin: K = zl*32 + (yl>>3)  (full x, 8 y-cells, 1 z-cell)
__device__ __forceinline__ int fine_bin3(float px, float py, float pz) {
    int xl, yl, zl; float tx, ty, tz;
    cell_of(px, xl, tx);
    cell_of(py, yl, ty);
    cell_of(pz, zl, tz);
    return (zl << 5) | (yl >> 3);
}

__device__ __forceinline__ void direct_lerp(const float* __restrict__ grid,
                                            float* __restrict__ out, int i,
                                            int xl, int yl, int zl,
                                            float tx, float ty, float tz) {
    int b00 = (zl * 65536 + yl * 256 + xl) * 3;
    int b01 = b00 + 768, b10 = b00 + 196608, b11 = b10 + 768;
    float s00[6], s01[6], s10[6], s11[6];
#pragma unroll
    for (int k = 0; k < 6; ++k) s00[k] = grid[b00 + k];
#pragma unroll
    for (int k = 0; k < 6; ++k) s01[k] = grid[b01 + k];
#pragma unroll
    for (int k = 0; k < 6; ++k) s10[k] = grid[b10 + k];
#pragma unroll
    for (int k = 0; k < 6; ++k) s11[k] = grid[b11 + k];
#pragma unroll
    for (int c = 0; c < 3; ++c) {
        float c00 = s00[c] * (1.0f - tx) + s00[c + 3] * tx;
        float c01 = s01[c] * (1.0f - tx) + s01[c + 3] * tx;
        float c10 = s10[c] * (1.0f - tx) + s10[c + 3] * tx;
        float c11 = s11[c] * (1.0f - tx) + s11[c + 3] * tx;
        float c0 = c00 * (1.0f - ty) + c01 * ty;
        float c1 = c10 * (1.0f - ty) + c11 * ty;
        out[3 * i + c] = c0 * (1.0f - tz) + c1 * tz;
    }
}

// ---------------- pass 0: init cursors to region bases ----------------
__global__ __launch_bounds__(1024) void k_init(unsigned* __restrict__ cur) {
    int i = blockIdx.x * 1024 + threadIdx.x;
    if (i < NB) cur[i] = (unsigned)i * CAP;
}

// ---------------- pass 1: block-aggregated scatter (2 pts/thread) ----------------
__global__ __launch_bounds__(1024) void k_scatter(const float* __restrict__ inp,
                                                  const float* __restrict__ grid,
                                                  float4* __restrict__ binned,
                                                  unsigned* __restrict__ cur,
                                                  float* __restrict__ out, int n) {
    __shared__ unsigned cnt[NB];
    __shared__ unsigned base[NB];
    int t = threadIdx.x;
    int P = n >> 1;
    int stride = gridDim.x * 1024;
    int iters = (P + stride - 1) / stride;

    if ((n & 1) && blockIdx.x == 0 && t == 0) {
        int i = n - 1;
        float px = inp[3 * i], py = inp[3 * i + 1], pz = inp[3 * i + 2];
        int b = fine_bin3(px, py, pz);
        unsigned r = atomicAdd(&cur[b], 1u);
        if (r - (unsigned)b * CAP < CAP) {
            float4 v; v.x = px; v.y = py; v.z = pz; v.w = __uint_as_float((unsigned)i);
            binned[r] = v;
        } else {
            int xl, yl, zl; float tx, ty, tz;
            cell_of(px, xl, tx); cell_of(py, yl, ty); cell_of(pz, zl, tz);
            direct_lerp(grid, out, i, xl, yl, zl, tx, ty, tz);
        }
    }

    for (int it = 0; it < iters; ++it) {
        int pr = it * stride + blockIdx.x * 1024 + t;
        for (int k = t; k < NB; k += 1024) cnt[k] = 0;
        __syncthreads();
        int b0 = 0, b1 = 0; unsigned r0 = 0, r1 = 0;
        float4 p0, p1;
        bool valid = (pr < P);
        if (valid) {
            f4v a = *(const f4u*)(inp + 6 * pr);
            f2v b = *(const f2u*)(inp + 6 * pr + 4);
            p0.x = a.x; p0.y = a.y; p0.z = a.z;
            p0.w = __uint_as_float((unsigned)(2 * pr));
            p1.x = a.w; p1.y = b.x; p1.z = b.y;
            p1.w = __uint_as_float((unsigned)(2 * pr + 1));
            b0 = fine_bin3(p0.x, p0.y, p0.z);
            b1 = fine_bin3(p1.x, p1.y, p1.z);
            r0 = atomicAdd(&cnt[b0], 1u);
            r1 = atomicAdd(&cnt[b1], 1u);
        }
        __syncthreads();
        for (int k = t; k < NB; k += 1024)
            if (cnt[k]) base[k] = atomicAdd(&cur[k], cnt[k]);
        __syncthreads();
        if (valid) {
            unsigned s0 = base[b0] + r0;
            unsigned s1 = base[b1] + r1;
            if (s0 - (unsigned)b0 * CAP < CAP) binned[s0] = p0;
            else {
                int xl, yl, zl; float tx, ty, tz;
                cell_of(p0.x, xl, tx); cell_of(p0.y, yl, ty); cell_of(p0.z, zl, tz);
                direct_lerp(grid, out, 2 * pr, xl, yl, zl, tx, ty, tz);
            }
            if (s1 - (unsigned)b1 * CAP < CAP) binned[s1] = p1;
            else {
                int xl, yl, zl; float tx, ty, tz;
                cell_of(p1.x, xl, tx); cell_of(p1.y, yl, ty); cell_of(p1.z, zl, tz);
                direct_lerp(grid, out, 2 * pr + 1, xl, yl, zl, tx, ty, tz);
            }
        }
        __syncthreads();
    }
}

// ---------------- pass 2: z-walk gather with rolling 3-layer window ----------------
// Stage one y-slab layer [zg][y0..y0+8][*] (27648 B, fully contiguous) into
// window slot `slot` as an LDS-linear global_load_lds stream.
#define STAGE_LAYER(zg_, slot_)                                                 \
    do {                                                                        \
        size_t basef4 = (size_t)(zg_)*49152 + (size_t)y0 * 192;                 \
        float* dst = &slab[(slot_) * LAYERF];                                   \
        for (int u = t; u < LAYERF4; u += GBLK) {                               \
            size_t sf4 = basef4 + (size_t)u;                                    \
            if (sf4 > (size_t)(GRIDF4 - 1)) sf4 = (size_t)(GRIDF4 - 1);         \
            __builtin_amdgcn_global_load_lds(                                   \
                (const __attribute__((address_space(1))) unsigned int*)(grid + sf4 * 4), \
                (__attribute__((address_space(3))) unsigned int*)&dst[(size_t)u * 4], \
                16, 0, 0);                                                      \
        }                                                                       \
    } while (0)

__global__ __launch_bounds__(GBLK) void k_gather(const float4* __restrict__ binned,
                                                 const float* __restrict__ grid,
                                                 const unsigned* __restrict__ cur,
                                                 float* __restrict__ out) {
    __shared__ __align__(16) float slab[3 * LAYERF];   // 82944 B
    int t = threadIdx.x;
    // 512 blocks; XCD-chunked: XCD k owns bins [64k, 64k+64) = 2 contiguous
    // z-bins x all y (halo layers shared within the XCD's L2).
    int bin = ((blockIdx.x & 7) << 6) | (blockIdx.x >> 3);   // bijective [0,512)
    int zb = bin >> 5;            // 16 z-segments of 16 cells
    int yb = bin & 31;            // 32 y-bins of 8 cells
    int z0 = zb << 4;
    int y0 = yb << 3;

    int zg1 = z0 + 1 > 255 ? 255 : z0 + 1;
    STAGE_LAYER(z0,  0);
    STAGE_LAYER(zg1, 1);

    for (int zc = 0; zc < 16; ++zc) {
        int sA = (zc % 3) * LAYERF;
        int sB = ((zc + 1) % 3) * LAYERF;
        // __syncthreads: s_waitcnt vmcnt(0) lgkmcnt(0) + s_barrier — drains
        // the stage for layer zc+1 and fences slot (zc+2)%3's last readers.
        __syncthreads();
        if (zc < 15) {
            int zg = z0 + zc + 2; zg = zg > 255 ? 255 : zg;
            STAGE_LAYER(zg, (zc + 2) % 3);
        }

        int K = ((z0 + zc) << 5) | yb;
        unsigned start = (unsigned)K * CAP;
        unsigned count = cur[K] - start;
        if (count > CAP) count = CAP;

        for (unsigned p = (unsigned)t; p < count; p += (unsigned)GBLK) {
            float4 v = binned[start + p];
            unsigned idx = __float_as_uint(v.w);

            int xl, yl, zl; float tx, ty, tz;
            cell_of(v.x, xl, tx);
            cell_of(v.y, yl, ty);
            cell_of(v.z, zl, tz);
            int row = yl - y0;                 // 0..7

            int o00 = sA + row * 768 + xl * 3;
            int o01 = o00 + 768;
            int o10 = sB + row * 768 + xl * 3;
            int o11 = o10 + 768;

#define SEG_READ(b, s)                                   \
            do {                                         \
                int e_ = (b) & ~1;                       \
                bool d_ = ((b) & 1) != 0;                \
                f2v q0 = *(const f2u*)(&slab[e_]);       \
                f2v q1 = *(const f2u*)(&slab[e_ + 2]);   \
                f2v q2 = *(const f2u*)(&slab[e_ + 4]);   \
                f2v q3 = *(const f2u*)(&slab[e_ + 6]);   \
                s[0] = d_ ? q0.y : q0.x;                 \
                s[1] = d_ ? q1.x : q0.y;                 \
                s[2] = d_ ? q1.y : q1.x;                 \
                s[3] = d_ ? q2.x : q1.y;                 \
                s[4] = d_ ? q2.y : q2.x;                 \
                s[5] = d_ ? q3.x : q2.y;                 \
            } while (0)

            float s00[6], s01[6], s10[6], s11[6];
            SEG_READ(o00, s00);   // (zl,   yl)
            SEG_READ(o01, s01);   // (zl,   yl+1)
            SEG_READ(o10, s10);   // (zl+1, yl)
            SEG_READ(o11, s11);   // (zl+1, yl+1)
#undef SEG_READ

            float o[3];
#pragma unroll
            for (int c = 0; c < 3; ++c) {
                float c00 = s00[c] * (1.0f - tx) + s00[c + 3] * tx;
                float c01 = s01[c] * (1.0f - tx) + s01[c + 3] * tx;
                float c10 = s10[c] * (1.0f - tx) + s10[c + 3] * tx;
                float c11 = s11[c] * (1.0f - tx) + s11[c + 3] * tx;
                float c0 = c00 * (1.0f - ty) + c01 * ty;
                float c1 = c10 * (1.0f - ty) + c11 * ty;
                o[c] = c0 * (1.0f - tz) + c1 * tz;
            }
            float3 w; w.x = o[0]; w.y = o[1]; w.z = o[2];
            *(float3*)(out + 3 * (size_t)idx) = w;
        }
    }
}

// ---------------- fallback: direct ----------------
__global__ __launch_bounds__(256) void k_direct(const float* __restrict__ inp,
                                                const float* __restrict__ grid,
                                                float* __restrict__ out, int n) {
    int i = blockIdx.x * blockDim.x + threadIdx.x;
    if (i >= n) return;
    int xl, yl, zl; float tx, ty, tz;
    cell_of(inp[3 * i + 0], xl, tx);
    cell_of(inp[3 * i + 1], yl, ty);
    cell_of(inp[3 * i + 2], zl, tz);
    direct_lerp(grid, out, i, xl, yl, zl, tx, ty, tz);
}

extern "C" void kernel_launch(void* const* d_in, const int* in_sizes, int n_in,
                              void* d_out, int out_size, void* d_ws, size_t ws_size,
                              hipStream_t stream) {
    const float* inp  = (const float*)d_in[0];  // [N][3]
    const float* grid = (const float*)d_in[1];  // [256][256][256][3]
    float* out = (float*)d_out;                 // [N][3]
    int n = in_sizes[0] / 3;

    if (ws_size < (size_t)NEEDED) {
        int blocks = (n + 255) / 256;
        k_direct<<<blocks, 256, 0, stream>>>(inp, grid, out, n);
        return;
    }

    char* ws = (char*)d_ws;
    float4*   binned = (float4*)ws;
    unsigned* cur    = (unsigned*)(ws + CUR_OFF);

    k_init   <<<8,   1024, 0, stream>>>(cur);
    k_scatter<<<512, 1024, 0, stream>>>(inp, grid, binned, cur, out, n);
    k_gather <<<512, GBLK, 0, stream>>>(binned, grid, cur, out);
}